// Round 1
// baseline (434.546 us; speedup 1.0000x reference)
//
#include <hip/hip_runtime.h>
#include <stdint.h>

// ---- problem constants ----
// B=4, T=2048, W=1024, H=16, D=64; M = B*T = 8192; 3W = 3072
#define MM   8192
#define KK   1024
#define NQKV 3072
#define TT   2048
#define HH   16
#define DD   64

typedef __attribute__((ext_vector_type(8))) short bf16x8;
typedef __attribute__((ext_vector_type(4))) short short4v;
typedef __attribute__((ext_vector_type(4))) float f32x4;

#define MFMA16(a,b,c) __builtin_amdgcn_mfma_f32_16x16x32_bf16(a,b,c,0,0,0)

// fp32 -> bf16 RNE (finite inputs)
static __device__ __forceinline__ short f2bf(float f) {
    uint32_t u = __float_as_uint(f);
    uint32_t r = (u + 0x7fffu + ((u >> 16) & 1u)) >> 16;
    return (short)r;
}

// ---- kernel 1: x fp32 -> bf16 ----
__global__ __launch_bounds__(256) void convert_x(const float* __restrict__ x,
                                                 short* __restrict__ xb, int n) {
    int i = (blockIdx.x * 256 + threadIdx.x) * 4;
    if (i >= n) return;
    float4 v = *(const float4*)(x + i);
    short4v o;
    o[0] = f2bf(v.x); o[1] = f2bf(v.y); o[2] = f2bf(v.z); o[3] = f2bf(v.w);
    *(short4v*)(xb + i) = o;
}

// ---- kernel 2: W[K][N] fp32 -> Wt[N][K] bf16 (32x32 LDS tile) ----
__global__ __launch_bounds__(256) void transpose_w(const float* __restrict__ Wf,
                                                   short* __restrict__ Wt, int K, int N) {
    __shared__ float tile[32][33];
    const int n0 = blockIdx.x * 32, k0 = blockIdx.y * 32;
    const int tx = threadIdx.x & 31, ty = threadIdx.x >> 5;  // ty 0..7
#pragma unroll
    for (int i = 0; i < 4; ++i) {
        int k = ty + i * 8;
        tile[k][tx] = Wf[(size_t)(k0 + k) * N + n0 + tx];
    }
    __syncthreads();
#pragma unroll
    for (int i = 0; i < 4; ++i) {
        int n = ty + i * 8;
        Wt[(size_t)(n0 + n) * K + k0 + tx] = f2bf(tile[tx][n]);
    }
}

// ---- GEMM: C[M][N] = A[M][K] * Bt[N][K]^T + bias, bf16 in, fp32 acc ----
// 128x128 tile, BK=64, 256 threads = 4 waves (2x2), each wave 64x64 = 4x4 frags.
template <int N, bool F32OUT>
__global__ __launch_bounds__(256) void gemm_bt(const short* __restrict__ A,
                                               const short* __restrict__ Bt,
                                               const float* __restrict__ bias,
                                               void* __restrict__ Cout, int K) {
    __shared__ short As[128 * 72];   // [128 rows][64+8 k]  row=144B, 16B aligned
    __shared__ short Bs[128 * 72];
    const int tid = threadIdx.x, lane = tid & 63, wave = tid >> 6;
    const int l15 = lane & 15, lg = lane >> 4;
    const int wm = wave >> 1, wn = wave & 1;
    const int m0 = blockIdx.y * 128, n0 = blockIdx.x * 128;

    f32x4 zero = {0.f, 0.f, 0.f, 0.f};
    f32x4 acc[4][4];
#pragma unroll
    for (int i = 0; i < 4; ++i)
#pragma unroll
        for (int j = 0; j < 4; ++j) acc[i][j] = zero;

    const int sr = tid >> 3, sc = (tid & 7) * 8;  // stage: 32 rows/pass, 8 thr x 8 elem per row

    for (int kt = 0; kt < K; kt += 64) {
#pragma unroll
        for (int p = 0; p < 4; ++p) {
            int row = sr + p * 32;
            *(bf16x8*)(&As[row * 72 + sc]) = *(const bf16x8*)(A + (size_t)(m0 + row) * K + kt + sc);
            *(bf16x8*)(&Bs[row * 72 + sc]) = *(const bf16x8*)(Bt + (size_t)(n0 + row) * K + kt + sc);
        }
        __syncthreads();
#pragma unroll
        for (int ks = 0; ks < 2; ++ks) {
            bf16x8 af[4], bfr[4];
#pragma unroll
            for (int i = 0; i < 4; ++i)
                af[i] = *(const bf16x8*)(&As[(wm * 64 + i * 16 + l15) * 72 + ks * 32 + lg * 8]);
#pragma unroll
            for (int j = 0; j < 4; ++j)
                bfr[j] = *(const bf16x8*)(&Bs[(wn * 64 + j * 16 + l15) * 72 + ks * 32 + lg * 8]);
#pragma unroll
            for (int i = 0; i < 4; ++i)
#pragma unroll
                for (int j = 0; j < 4; ++j)
                    acc[i][j] = MFMA16(af[i], bfr[j], acc[i][j]);
        }
        __syncthreads();
    }
    // epilogue: C layout col=lane&15, row=(lane>>4)*4+r
#pragma unroll
    for (int j = 0; j < 4; ++j) {
        int col = n0 + wn * 64 + j * 16 + l15;
        float bv = bias[col];
#pragma unroll
        for (int i = 0; i < 4; ++i) {
            int row = m0 + wm * 64 + i * 16 + lg * 4;
#pragma unroll
            for (int r = 0; r < 4; ++r) {
                float v = acc[i][j][r] + bv;
                if (F32OUT)
                    ((float*)Cout)[(size_t)(row + r) * N + col] = v;
                else
                    ((short*)Cout)[(size_t)(row + r) * N + col] = f2bf(v);
            }
        }
    }
}

// ---- kernel 4: extract V from QKV and transpose -> Vt[bh][d=64][s=2048] ----
__global__ __launch_bounds__(256) void transpose_v(const short* __restrict__ QKV,
                                                   short* __restrict__ Vt) {
    __shared__ short t[64 * 72];  // [s 64][d 64+8]
    const int sb = blockIdx.x * 64, bh = blockIdx.y;
    const int b = bh >> 4, h = bh & 15;
    const int tid = threadIdx.x;
    const int r = tid >> 3, c = (tid & 7) * 8;
#pragma unroll
    for (int p = 0; p < 2; ++p) {
        int row = r + p * 32;
        *(bf16x8*)(&t[row * 72 + c]) =
            *(const bf16x8*)(QKV + (size_t)(b * TT + sb + row) * NQKV + h * 192 + 128 + c);
    }
    __syncthreads();
    const int d = tid >> 3, s0 = (tid & 7) * 8;
#pragma unroll
    for (int p = 0; p < 2; ++p) {
        int dd = d + p * 32;
        bf16x8 w;
#pragma unroll
        for (int j = 0; j < 8; ++j) w[j] = t[(s0 + j) * 72 + dd];
        *(bf16x8*)(Vt + ((size_t)bh * DD + dd) * TT + sb + s0) = w;
    }
}

// ---- kernel 5: flash attention ----
// grid (32 qblocks, 64 bh), 256 thr = 4 waves, each wave 16 q-rows; 32-key blocks.
__global__ __launch_bounds__(256) void attn_fwd(const short* __restrict__ QKV,
                                                const short* __restrict__ Vt,
                                                short* __restrict__ Out) {
    __shared__ short Ks[32 * 72];      // [32 keys][64+8 d]
    __shared__ short Vs[64 * 40];      // [64 d][32+8 keys]
    __shared__ short Ps[4][16 * 40];   // per-wave [16 q][32+8 keys]
    const int qb = blockIdx.x, bh = blockIdx.y;
    const int b = bh >> 4, h = bh & 15;
    const int tid = threadIdx.x, lane = tid & 63, wave = tid >> 6;
    const int l15 = lane & 15, lg = lane >> 4;

    // Q fragments stay in registers: A-frag row=lane&15, k(d)=(lane>>4)*8+j
    const short* qptr = QKV + (size_t)(b * TT + qb * 64 + wave * 16 + l15) * NQKV + h * 192 + lg * 8;
    const bf16x8 qf0 = *(const bf16x8*)(qptr);
    const bf16x8 qf1 = *(const bf16x8*)(qptr + 32);

    f32x4 zero = {0.f, 0.f, 0.f, 0.f};
    f32x4 acc[4];
    float m[4], ls[4];
#pragma unroll
    for (int r = 0; r < 4; ++r) { acc[r] = zero; m[r] = -1e30f; ls[r] = 0.f; }

    const int skr = tid >> 3, skc = (tid & 7) * 8;      // K stage: 32 rows x (8thr x 8)
    const int svr = tid >> 2, svc = (tid & 3) * 8;      // V stage: 64 rows x (4thr x 8)
    const short* kbase = QKV + (size_t)(b * TT + skr) * NQKV + h * 192 + 64 + skc;
    const short* vbase = Vt + ((size_t)bh * DD + svr) * TT + svc;

    for (int kb = 0; kb < TT; kb += 32) {
        *(bf16x8*)(&Ks[skr * 72 + skc]) = *(const bf16x8*)(kbase + (size_t)kb * NQKV);
        *(bf16x8*)(&Vs[svr * 40 + svc]) = *(const bf16x8*)(vbase + kb);
        __syncthreads();

        // S = Q K^T for 2 halves of 16 keys
        f32x4 s[2];
#pragma unroll
        for (int hh = 0; hh < 2; ++hh) {
            bf16x8 k0 = *(const bf16x8*)(&Ks[(hh * 16 + l15) * 72 + lg * 8]);
            bf16x8 k1 = *(const bf16x8*)(&Ks[(hh * 16 + l15) * 72 + 32 + lg * 8]);
            f32x4 t = zero;
            t = MFMA16(qf0, k0, t);
            t = MFMA16(qf1, k1, t);
            s[hh] = t;
        }
#pragma unroll
        for (int hh = 0; hh < 2; ++hh)
#pragma unroll
            for (int r = 0; r < 4; ++r) s[hh][r] *= 0.125f;

        float p0[4], p1[4], alpha[4];
#pragma unroll
        for (int r = 0; r < 4; ++r) {
            float v = fmaxf(s[0][r], s[1][r]);
            v = fmaxf(v, __shfl_xor(v, 1));
            v = fmaxf(v, __shfl_xor(v, 2));
            v = fmaxf(v, __shfl_xor(v, 4));
            v = fmaxf(v, __shfl_xor(v, 8));
            float nm = fmaxf(m[r], v);
            alpha[r] = __expf(m[r] - nm);
            m[r] = nm;
            p0[r] = __expf(s[0][r] - nm);
            p1[r] = __expf(s[1][r] - nm);
            float rs = p0[r] + p1[r];
            rs += __shfl_xor(rs, 1);
            rs += __shfl_xor(rs, 2);
            rs += __shfl_xor(rs, 4);
            rs += __shfl_xor(rs, 8);
            ls[r] = ls[r] * alpha[r] + rs;
        }
#pragma unroll
        for (int nt = 0; nt < 4; ++nt)
#pragma unroll
            for (int r = 0; r < 4; ++r) acc[nt][r] *= alpha[r];

        // P -> per-wave LDS (transpose C-layout -> A-frag layout)
        short* pw = &Ps[wave][0];
#pragma unroll
        for (int r = 0; r < 4; ++r) {
            pw[(lg * 4 + r) * 40 + l15] = f2bf(p0[r]);
            pw[(lg * 4 + r) * 40 + 16 + l15] = f2bf(p1[r]);
        }
        __syncthreads();
        bf16x8 pf = *(const bf16x8*)(&Ps[wave][l15 * 40 + lg * 8]);
#pragma unroll
        for (int nt = 0; nt < 4; ++nt) {
            bf16x8 vf = *(const bf16x8*)(&Vs[(nt * 16 + l15) * 40 + lg * 8]);
            acc[nt] = MFMA16(pf, vf, acc[nt]);
        }
        __syncthreads();
    }

    // write attn output (bf16), row = token, col = h*64 + d
#pragma unroll
    for (int nt = 0; nt < 4; ++nt) {
        int col = h * DD + nt * 16 + l15;
#pragma unroll
        for (int r = 0; r < 4; ++r) {
            int row = b * TT + qb * 64 + wave * 16 + lg * 4 + r;
            Out[(size_t)row * (HH * DD) + col] = f2bf(acc[nt][r] / ls[r]);
        }
    }
}

extern "C" void kernel_launch(void* const* d_in, const int* in_sizes, int n_in,
                              void* d_out, int out_size, void* d_ws, size_t ws_size,
                              hipStream_t stream) {
    const float* x      = (const float*)d_in[0];
    const float* w_qkv  = (const float*)d_in[1];
    const float* b_qkv  = (const float*)d_in[2];
    const float* w_proj = (const float*)d_in[3];
    const float* b_proj = (const float*)d_in[4];
    float* out = (float*)d_out;

    char* ws = (char*)d_ws;
    short* xb     = (short*)(ws);                         // 8192*1024*2  = 16777216
    short* wqkvt  = (short*)(ws + 16777216);              // 3072*1024*2  =  6291456
    short* wprojt = (short*)(ws + 23068672);              // 1024*1024*2  =  2097152
    short* qkv    = (short*)(ws + 25165824);              // 8192*3072*2  = 50331648
    short* vt     = (short*)(ws + 75497472);              // 64*64*2048*2 = 16777216
    short* ao     = (short*)(ws + 92274688);              // 8192*1024*2  = 16777216

    convert_x<<<8192, 256, 0, stream>>>(x, xb, MM * KK);
    transpose_w<<<dim3(NQKV / 32, KK / 32), 256, 0, stream>>>(w_qkv, wqkvt, KK, NQKV);
    transpose_w<<<dim3(KK / 32, KK / 32), 256, 0, stream>>>(w_proj, wprojt, KK, KK);
    gemm_bt<NQKV, false><<<dim3(NQKV / 128, MM / 128), 256, 0, stream>>>(xb, wqkvt, b_qkv, qkv, KK);
    transpose_v<<<dim3(TT / 64, 64), 256, 0, stream>>>(qkv, vt);
    attn_fwd<<<dim3(TT / 64, 64), 256, 0, stream>>>(qkv, vt, ao);
    gemm_bt<KK, true><<<dim3(KK / 128, MM / 128), 256, 0, stream>>>(ao, wprojt, b_proj, out, KK);
}

// Round 3
// 417.108 us; speedup vs baseline: 1.0418x; 1.0418x over previous
//
#include <hip/hip_runtime.h>
#include <stdint.h>

// ---- problem constants ----
// B=4, T=2048, W=1024, H=16, D=64; M = B*T = 8192; 3W = 3072
#define MM   8192
#define KK   1024
#define NQKV 3072
#define TT   2048
#define HH   16
#define DD   64

typedef __attribute__((ext_vector_type(8))) short bf16x8;
typedef __attribute__((ext_vector_type(4))) short short4v;
typedef __attribute__((ext_vector_type(4))) float f32x4;
typedef __attribute__((ext_vector_type(16))) float f32x16;
typedef __attribute__((ext_vector_type(4))) unsigned int u32x4;

#define MFMA16(a,b,c)  __builtin_amdgcn_mfma_f32_16x16x32_bf16(a,b,c,0,0,0)
#define MFMA32(a,b,c)  __builtin_amdgcn_mfma_f32_32x32x16_bf16(a,b,c,0,0,0)

// fp32 -> bf16 RNE (finite inputs)
static __device__ __forceinline__ short f2bf(float f) {
    uint32_t u = __float_as_uint(f);
    uint32_t r = (u + 0x7fffu + ((u >> 16) & 1u)) >> 16;
    return (short)r;
}

// v_cvt_pk_bf16_f32: dst = {bf16(a) lo, bf16(b) hi}
static __device__ __forceinline__ uint32_t cvtpk(float a, float b) {
    uint32_t r;
    asm("v_cvt_pk_bf16_f32 %0, %1, %2" : "=v"(r) : "v"(a), "v"(b));
    return r;
}

// v_permlane32_swap_b32: x[32:63] <-> y[0:31]
// NOTE: only safe when x and y hold distinct values (else regalloc may alias
// them into one VGPR and the swap degenerates). Reductions use __shfl_xor.
static __device__ __forceinline__ void plswap(uint32_t& x, uint32_t& y) {
    asm("v_permlane32_swap_b32 %0, %1" : "+v"(x), "+v"(y));
}

// ---- kernel 1: x fp32 -> bf16 ----
__global__ __launch_bounds__(256) void convert_x(const float* __restrict__ x,
                                                 short* __restrict__ xb, int n) {
    int i = (blockIdx.x * 256 + threadIdx.x) * 4;
    if (i >= n) return;
    float4 v = *(const float4*)(x + i);
    short4v o;
    o[0] = f2bf(v.x); o[1] = f2bf(v.y); o[2] = f2bf(v.z); o[3] = f2bf(v.w);
    *(short4v*)(xb + i) = o;
}

// ---- kernel 2: W[K][N] fp32 -> Wt[N][K] bf16 (32x32 LDS tile) ----
__global__ __launch_bounds__(256) void transpose_w(const float* __restrict__ Wf,
                                                   short* __restrict__ Wt, int K, int N) {
    __shared__ float tile[32][33];
    const int n0 = blockIdx.x * 32, k0 = blockIdx.y * 32;
    const int tx = threadIdx.x & 31, ty = threadIdx.x >> 5;  // ty 0..7
#pragma unroll
    for (int i = 0; i < 4; ++i) {
        int k = ty + i * 8;
        tile[k][tx] = Wf[(size_t)(k0 + k) * N + n0 + tx];
    }
    __syncthreads();
#pragma unroll
    for (int i = 0; i < 4; ++i) {
        int n = ty + i * 8;
        Wt[(size_t)(n0 + n) * K + k0 + tx] = f2bf(tile[tx][n]);
    }
}

// ---- GEMM: C[M][N] = A[M][K] * Bt[N][K]^T + bias, bf16 in, fp32 acc ----
template <int N, bool F32OUT>
__global__ __launch_bounds__(256) void gemm_bt(const short* __restrict__ A,
                                               const short* __restrict__ Bt,
                                               const float* __restrict__ bias,
                                               void* __restrict__ Cout, int K) {
    __shared__ short As[128 * 72];
    __shared__ short Bs[128 * 72];
    const int tid = threadIdx.x, lane = tid & 63, wave = tid >> 6;
    const int l15 = lane & 15, lg = lane >> 4;
    const int wm = wave >> 1, wn = wave & 1;
    const int m0 = blockIdx.y * 128, n0 = blockIdx.x * 128;

    f32x4 zero = {0.f, 0.f, 0.f, 0.f};
    f32x4 acc[4][4];
#pragma unroll
    for (int i = 0; i < 4; ++i)
#pragma unroll
        for (int j = 0; j < 4; ++j) acc[i][j] = zero;

    const int sr = tid >> 3, sc = (tid & 7) * 8;

    for (int kt = 0; kt < K; kt += 64) {
#pragma unroll
        for (int p = 0; p < 4; ++p) {
            int row = sr + p * 32;
            *(bf16x8*)(&As[row * 72 + sc]) = *(const bf16x8*)(A + (size_t)(m0 + row) * K + kt + sc);
            *(bf16x8*)(&Bs[row * 72 + sc]) = *(const bf16x8*)(Bt + (size_t)(n0 + row) * K + kt + sc);
        }
        __syncthreads();
#pragma unroll
        for (int ks = 0; ks < 2; ++ks) {
            bf16x8 af[4], bfr[4];
#pragma unroll
            for (int i = 0; i < 4; ++i)
                af[i] = *(const bf16x8*)(&As[(wm * 64 + i * 16 + l15) * 72 + ks * 32 + lg * 8]);
#pragma unroll
            for (int j = 0; j < 4; ++j)
                bfr[j] = *(const bf16x8*)(&Bs[(wn * 64 + j * 16 + l15) * 72 + ks * 32 + lg * 8]);
#pragma unroll
            for (int i = 0; i < 4; ++i)
#pragma unroll
                for (int j = 0; j < 4; ++j)
                    acc[i][j] = MFMA16(af[i], bfr[j], acc[i][j]);
        }
        __syncthreads();
    }
#pragma unroll
    for (int j = 0; j < 4; ++j) {
        int col = n0 + wn * 64 + j * 16 + l15;
        float bv = bias[col];
#pragma unroll
        for (int i = 0; i < 4; ++i) {
            int row = m0 + wm * 64 + i * 16 + lg * 4;
#pragma unroll
            for (int r = 0; r < 4; ++r) {
                float v = acc[i][j][r] + bv;
                if (F32OUT)
                    ((float*)Cout)[(size_t)(row + r) * N + col] = v;
                else
                    ((short*)Cout)[(size_t)(row + r) * N + col] = f2bf(v);
            }
        }
    }
}

// ---- kernel 4: extract V from QKV and transpose -> Vt[bh][d=64][s=2048] ----
__global__ __launch_bounds__(256) void transpose_v(const short* __restrict__ QKV,
                                                   short* __restrict__ Vt) {
    __shared__ short t[64 * 72];
    const int sb = blockIdx.x * 64, bh = blockIdx.y;
    const int b = bh >> 4, h = bh & 15;
    const int tid = threadIdx.x;
    const int r = tid >> 3, c = (tid & 7) * 8;
#pragma unroll
    for (int p = 0; p < 2; ++p) {
        int row = r + p * 32;
        *(bf16x8*)(&t[row * 72 + c]) =
            *(const bf16x8*)(QKV + (size_t)(b * TT + sb + row) * NQKV + h * 192 + 128 + c);
    }
    __syncthreads();
    const int d = tid >> 3, s0 = (tid & 7) * 8;
#pragma unroll
    for (int p = 0; p < 2; ++p) {
        int dd = d + p * 32;
        bf16x8 w;
#pragma unroll
        for (int j = 0; j < 8; ++j) w[j] = t[(s0 + j) * 72 + dd];
        *(bf16x8*)(Vt + ((size_t)bh * DD + dd) * TT + sb + s0) = w;
    }
}

// ---- kernel 5: flash attention, swapped-operand 32x32, no LDS, no barriers ----
// grid (16 qblocks, 64 bh), 256 thr = 4 waves; each wave owns 32 q-rows, KVBLK=64.
__global__ __launch_bounds__(256) void attn_fwd(const short* __restrict__ QKV,
                                                const short* __restrict__ Vt,
                                                short* __restrict__ Out) {
    const int qb = blockIdx.x, bh = blockIdx.y;
    const int b = bh >> 4, h = bh & 15;
    const int lane = threadIdx.x & 63, wave = threadIdx.x >> 6;
    const int l31 = lane & 31, hi = lane >> 5;
    const int q0 = qb * 128 + wave * 32;

    // Q fragments (B-operand: col=lane&31=q, k=d=(lane>>5)*8+j), 4 d-chunks of 16
    const short* qptr = QKV + (size_t)(b * TT + q0 + l31) * NQKV + h * 192 + hi * 8;
    bf16x8 qf[4];
#pragma unroll
    for (int dc = 0; dc < 4; ++dc) qf[dc] = *(const bf16x8*)(qptr + dc * 16);

    const short* kbase = QKV + (size_t)(b * TT + l31) * NQKV + h * 192 + 64 + hi * 8;
    const short* vbase = Vt + ((size_t)bh * DD + l31) * TT + hi * 8;

    f32x16 o0, o1;
#pragma unroll
    for (int i = 0; i < 16; ++i) { o0[i] = 0.f; o1[i] = 0.f; }
    float m2 = -1e30f, ls = 0.f;
    const float cc = 0.18033688011112042f;  // 0.125 * log2(e)

    for (int kb = 0; kb < TT; kb += 64) {
        // S^T tiles: s0 = keys kb..kb+31, s1 = keys kb+32..kb+63 (A=K rows, B=Q)
        const short* kp = kbase + (size_t)kb * NQKV;
        bf16x8 kf0[4], kf1[4];
#pragma unroll
        for (int dc = 0; dc < 4; ++dc) kf0[dc] = *(const bf16x8*)(kp + dc * 16);
#pragma unroll
        for (int dc = 0; dc < 4; ++dc) kf1[dc] = *(const bf16x8*)(kp + (size_t)32 * NQKV + dc * 16);
        f32x16 s0, s1;
#pragma unroll
        for (int i = 0; i < 16; ++i) { s0[i] = 0.f; s1[i] = 0.f; }
#pragma unroll
        for (int dc = 0; dc < 4; ++dc) s0 = MFMA32(kf0[dc], qf[dc], s0);
#pragma unroll
        for (int dc = 0; dc < 4; ++dc) s1 = MFMA32(kf1[dc], qf[dc], s1);

        // V^T fragments (A-operand for PV): rows d, k-slices of keys
        const short* vp = vbase + kb;
        bf16x8 vf0[4], vf1[4];
#pragma unroll
        for (int ks = 0; ks < 4; ++ks) vf0[ks] = *(const bf16x8*)(vp + ks * 16);
#pragma unroll
        for (int ks = 0; ks < 4; ++ks) vf1[ks] = *(const bf16x8*)(vp + (size_t)32 * TT + ks * 16);

        // ---- in-register online softmax (per lane = one q-row, 32 k-values) ----
        float mx = s0[0];
#pragma unroll
        for (int i = 1; i < 16; ++i) mx = fmaxf(mx, s0[i]);
#pragma unroll
        for (int i = 0; i < 16; ++i) mx = fmaxf(mx, s1[i]);
        mx = fmaxf(mx, __shfl_xor(mx, 32));   // combine hi/lo half (same q-row)
        float pm2 = mx * cc;
        if (!__all(pm2 - m2 <= 8.0f)) {   // defer-max (T13)
            float nm2 = fmaxf(m2, pm2);
            float alpha = exp2f(m2 - nm2);
            m2 = nm2;
#pragma unroll
            for (int i = 0; i < 16; ++i) { o0[i] *= alpha; o1[i] *= alpha; }
            ls *= alpha;
        }
        float p0[16], p1[16];
#pragma unroll
        for (int i = 0; i < 16; ++i) p0[i] = exp2f(fmaf(s0[i], cc, -m2));
#pragma unroll
        for (int i = 0; i < 16; ++i) p1[i] = exp2f(fmaf(s1[i], cc, -m2));
        float rs = p0[0];
#pragma unroll
        for (int i = 1; i < 16; ++i) rs += p0[i];
#pragma unroll
        for (int i = 0; i < 16; ++i) rs += p1[i];
        rs += __shfl_xor(rs, 32);             // combine hi/lo half (same q-row)
        ls += rs;

        // ---- P -> bf16 A/B fragments via cvt_pk + permlane32_swap (T12) ----
        uint32_t a0 = cvtpk(p0[0], p0[1]),  a1 = cvtpk(p0[2], p0[3]);
        uint32_t b0 = cvtpk(p0[4], p0[5]),  b1 = cvtpk(p0[6], p0[7]);
        plswap(a0, b0); plswap(a1, b1);
        uint32_t c0 = cvtpk(p0[8], p0[9]),  c1 = cvtpk(p0[10], p0[11]);
        uint32_t d0 = cvtpk(p0[12], p0[13]), d1 = cvtpk(p0[14], p0[15]);
        plswap(c0, d0); plswap(c1, d1);
        uint32_t e0 = cvtpk(p1[0], p1[1]),  e1 = cvtpk(p1[2], p1[3]);
        uint32_t f0 = cvtpk(p1[4], p1[5]),  f1 = cvtpk(p1[6], p1[7]);
        plswap(e0, f0); plswap(e1, f1);
        uint32_t g0 = cvtpk(p1[8], p1[9]),  g1 = cvtpk(p1[10], p1[11]);
        uint32_t h0 = cvtpk(p1[12], p1[13]), h1 = cvtpk(p1[14], p1[15]);
        plswap(g0, h0); plswap(g1, h1);
        u32x4 w0 = {a0, a1, b0, b1};
        u32x4 w1 = {c0, c1, d0, d1};
        u32x4 w2 = {e0, e1, f0, f1};
        u32x4 w3 = {g0, g1, h0, h1};
        bf16x8 pa0 = __builtin_bit_cast(bf16x8, w0);
        bf16x8 pa1 = __builtin_bit_cast(bf16x8, w1);
        bf16x8 pa2 = __builtin_bit_cast(bf16x8, w2);
        bf16x8 pa3 = __builtin_bit_cast(bf16x8, w3);

        // ---- PV: O^T += V^T * P^T (col=q stays lane-local) ----
        o0 = MFMA32(vf0[0], pa0, o0);
        o0 = MFMA32(vf0[1], pa1, o0);
        o0 = MFMA32(vf0[2], pa2, o0);
        o0 = MFMA32(vf0[3], pa3, o0);
        o1 = MFMA32(vf1[0], pa0, o1);
        o1 = MFMA32(vf1[1], pa1, o1);
        o1 = MFMA32(vf1[2], pa2, o1);
        o1 = MFMA32(vf1[3], pa3, o1);
    }

    // epilogue: lane owns q = q0+l31; d = (reg&3) + 8*(reg>>2) + 4*hi (+32 for o1)
    float inv = 1.0f / ls;
    short* orow = Out + (size_t)(b * TT + q0 + l31) * (HH * DD) + h * DD;
#pragma unroll
    for (int g = 0; g < 4; ++g) {
        short4v v0, v1;
#pragma unroll
        for (int r = 0; r < 4; ++r) {
            v0[r] = f2bf(o0[g * 4 + r] * inv);
            v1[r] = f2bf(o1[g * 4 + r] * inv);
        }
        *(short4v*)(orow + g * 8 + hi * 4) = v0;
        *(short4v*)(orow + 32 + g * 8 + hi * 4) = v1;
    }
}

extern "C" void kernel_launch(void* const* d_in, const int* in_sizes, int n_in,
                              void* d_out, int out_size, void* d_ws, size_t ws_size,
                              hipStream_t stream) {
    const float* x      = (const float*)d_in[0];
    const float* w_qkv  = (const float*)d_in[1];
    const float* b_qkv  = (const float*)d_in[2];
    const float* w_proj = (const float*)d_in[3];
    const float* b_proj = (const float*)d_in[4];
    float* out = (float*)d_out;

    char* ws = (char*)d_ws;
    short* xb     = (short*)(ws);                         // 16777216
    short* wqkvt  = (short*)(ws + 16777216);              //  6291456
    short* wprojt = (short*)(ws + 23068672);              //  2097152
    short* qkv    = (short*)(ws + 25165824);              // 50331648
    short* vt     = (short*)(ws + 75497472);              // 16777216
    short* ao     = (short*)(ws + 92274688);              // 16777216

    convert_x<<<8192, 256, 0, stream>>>(x, xb, MM * KK);
    transpose_w<<<dim3(NQKV / 32, KK / 32), 256, 0, stream>>>(w_qkv, wqkvt, KK, NQKV);
    transpose_w<<<dim3(KK / 32, KK / 32), 256, 0, stream>>>(w_proj, wprojt, KK, KK);
    gemm_bt<NQKV, false><<<dim3(NQKV / 128, MM / 128), 256, 0, stream>>>(xb, wqkvt, b_qkv, qkv, KK);
    transpose_v<<<dim3(TT / 64, 64), 256, 0, stream>>>(qkv, vt);
    attn_fwd<<<dim3(TT / 128, 64), 256, 0, stream>>>(qkv, vt, ao);
    gemm_bt<KK, true><<<dim3(KK / 128, MM / 128), 256, 0, stream>>>(ao, wprojt, b_proj, out, KK);
}

// Round 4
// 361.096 us; speedup vs baseline: 1.2034x; 1.1551x over previous
//
#include <hip/hip_runtime.h>
#include <stdint.h>

// ---- problem constants ----
// B=4, T=2048, W=1024, H=16, D=64; M = B*T = 8192; 3W = 3072
#define MM   8192
#define KK   1024
#define NQKV 3072
#define TT   2048
#define HH   16
#define DD   64

typedef __attribute__((ext_vector_type(8))) short bf16x8;
typedef __attribute__((ext_vector_type(4))) short short4v;
typedef __attribute__((ext_vector_type(4))) float f32x4;
typedef __attribute__((ext_vector_type(16))) float f32x16;
typedef __attribute__((ext_vector_type(4))) unsigned int u32x4;

#define MFMA16(a,b,c)  __builtin_amdgcn_mfma_f32_16x16x32_bf16(a,b,c,0,0,0)
#define MFMA32(a,b,c)  __builtin_amdgcn_mfma_f32_32x32x16_bf16(a,b,c,0,0,0)

// fp32 -> bf16 RNE (finite inputs)
static __device__ __forceinline__ short f2bf(float f) {
    uint32_t u = __float_as_uint(f);
    uint32_t r = (u + 0x7fffu + ((u >> 16) & 1u)) >> 16;
    return (short)r;
}

// v_cvt_pk_bf16_f32: dst = {bf16(a) lo, bf16(b) hi}
static __device__ __forceinline__ uint32_t cvtpk(float a, float b) {
    uint32_t r;
    asm("v_cvt_pk_bf16_f32 %0, %1, %2" : "=v"(r) : "v"(a), "v"(b));
    return r;
}

// v_permlane32_swap_b32: x[32:63] <-> y[0:31]
// Only safe when x,y hold distinct values (else regalloc may alias them).
static __device__ __forceinline__ void plswap(uint32_t& x, uint32_t& y) {
    asm("v_permlane32_swap_b32 %0, %1" : "+v"(x), "+v"(y));
}

// tree max of 16 (depth 4)
static __device__ __forceinline__ float tmax16(const f32x16& v) {
    float a0 = fmaxf(v[0], v[8]),  a1 = fmaxf(v[1], v[9]);
    float a2 = fmaxf(v[2], v[10]), a3 = fmaxf(v[3], v[11]);
    float a4 = fmaxf(v[4], v[12]), a5 = fmaxf(v[5], v[13]);
    float a6 = fmaxf(v[6], v[14]), a7 = fmaxf(v[7], v[15]);
    float b0 = fmaxf(a0, a4), b1 = fmaxf(a1, a5);
    float b2 = fmaxf(a2, a6), b3 = fmaxf(a3, a7);
    return fmaxf(fmaxf(b0, b2), fmaxf(b1, b3));
}

// tree sum of 16 (depth 4)
static __device__ __forceinline__ float tsum16(const float* p) {
    float a0 = p[0] + p[8],  a1 = p[1] + p[9];
    float a2 = p[2] + p[10], a3 = p[3] + p[11];
    float a4 = p[4] + p[12], a5 = p[5] + p[13];
    float a6 = p[6] + p[14], a7 = p[7] + p[15];
    float b0 = a0 + a4, b1 = a1 + a5, b2 = a2 + a6, b3 = a3 + a7;
    return (b0 + b2) + (b1 + b3);
}

// ---- kernel 1: x fp32 -> bf16 ----
__global__ __launch_bounds__(256) void convert_x(const float* __restrict__ x,
                                                 short* __restrict__ xb, int n) {
    int i = (blockIdx.x * 256 + threadIdx.x) * 4;
    if (i >= n) return;
    float4 v = *(const float4*)(x + i);
    short4v o;
    o[0] = f2bf(v.x); o[1] = f2bf(v.y); o[2] = f2bf(v.z); o[3] = f2bf(v.w);
    *(short4v*)(xb + i) = o;
}

// ---- kernel 2: W[K][N] fp32 -> Wt[N][K] bf16 (32x32 LDS tile) ----
__global__ __launch_bounds__(256) void transpose_w(const float* __restrict__ Wf,
                                                   short* __restrict__ Wt, int K, int N) {
    __shared__ float tile[32][33];
    const int n0 = blockIdx.x * 32, k0 = blockIdx.y * 32;
    const int tx = threadIdx.x & 31, ty = threadIdx.x >> 5;  // ty 0..7
#pragma unroll
    for (int i = 0; i < 4; ++i) {
        int k = ty + i * 8;
        tile[k][tx] = Wf[(size_t)(k0 + k) * N + n0 + tx];
    }
    __syncthreads();
#pragma unroll
    for (int i = 0; i < 4; ++i) {
        int n = ty + i * 8;
        Wt[(size_t)(n0 + n) * K + k0 + tx] = f2bf(tile[tx][n]);
    }
}

// ---- GEMM: C[M][N] = A[M][K] * Bt[N][K]^T + bias, bf16 in, fp32 acc ----
template <int N, bool F32OUT>
__global__ __launch_bounds__(256) void gemm_bt(const short* __restrict__ A,
                                               const short* __restrict__ Bt,
                                               const float* __restrict__ bias,
                                               void* __restrict__ Cout, int K) {
    __shared__ short As[128 * 72];
    __shared__ short Bs[128 * 72];
    const int tid = threadIdx.x, lane = tid & 63, wave = tid >> 6;
    const int l15 = lane & 15, lg = lane >> 4;
    const int wm = wave >> 1, wn = wave & 1;
    const int m0 = blockIdx.y * 128, n0 = blockIdx.x * 128;

    f32x4 zero = {0.f, 0.f, 0.f, 0.f};
    f32x4 acc[4][4];
#pragma unroll
    for (int i = 0; i < 4; ++i)
#pragma unroll
        for (int j = 0; j < 4; ++j) acc[i][j] = zero;

    const int sr = tid >> 3, sc = (tid & 7) * 8;

    for (int kt = 0; kt < K; kt += 64) {
#pragma unroll
        for (int p = 0; p < 4; ++p) {
            int row = sr + p * 32;
            *(bf16x8*)(&As[row * 72 + sc]) = *(const bf16x8*)(A + (size_t)(m0 + row) * K + kt + sc);
            *(bf16x8*)(&Bs[row * 72 + sc]) = *(const bf16x8*)(Bt + (size_t)(n0 + row) * K + kt + sc);
        }
        __syncthreads();
#pragma unroll
        for (int ks = 0; ks < 2; ++ks) {
            bf16x8 af[4], bfr[4];
#pragma unroll
            for (int i = 0; i < 4; ++i)
                af[i] = *(const bf16x8*)(&As[(wm * 64 + i * 16 + l15) * 72 + ks * 32 + lg * 8]);
#pragma unroll
            for (int j = 0; j < 4; ++j)
                bfr[j] = *(const bf16x8*)(&Bs[(wn * 64 + j * 16 + l15) * 72 + ks * 32 + lg * 8]);
#pragma unroll
            for (int i = 0; i < 4; ++i)
#pragma unroll
                for (int j = 0; j < 4; ++j)
                    acc[i][j] = MFMA16(af[i], bfr[j], acc[i][j]);
        }
        __syncthreads();
    }
#pragma unroll
    for (int j = 0; j < 4; ++j) {
        int col = n0 + wn * 64 + j * 16 + l15;
        float bv = bias[col];
#pragma unroll
        for (int i = 0; i < 4; ++i) {
            int row = m0 + wm * 64 + i * 16 + lg * 4;
#pragma unroll
            for (int r = 0; r < 4; ++r) {
                float v = acc[i][j][r] + bv;
                if (F32OUT)
                    ((float*)Cout)[(size_t)(row + r) * N + col] = v;
                else
                    ((short*)Cout)[(size_t)(row + r) * N + col] = f2bf(v);
            }
        }
    }
}

// ---- kernel 4: extract V from QKV and transpose -> Vt[bh][d=64][s=2048] ----
__global__ __launch_bounds__(256) void transpose_v(const short* __restrict__ QKV,
                                                   short* __restrict__ Vt) {
    __shared__ short t[64 * 72];
    const int sb = blockIdx.x * 64, bh = blockIdx.y;
    const int b = bh >> 4, h = bh & 15;
    const int tid = threadIdx.x;
    const int r = tid >> 3, c = (tid & 7) * 8;
#pragma unroll
    for (int p = 0; p < 2; ++p) {
        int row = r + p * 32;
        *(bf16x8*)(&t[row * 72 + c]) =
            *(const bf16x8*)(QKV + (size_t)(b * TT + sb + row) * NQKV + h * 192 + 128 + c);
    }
    __syncthreads();
    const int d = tid >> 3, s0 = (tid & 7) * 8;
#pragma unroll
    for (int p = 0; p < 2; ++p) {
        int dd = d + p * 32;
        bf16x8 w;
#pragma unroll
        for (int j = 0; j < 8; ++j) w[j] = t[(s0 + j) * 72 + dd];
        *(bf16x8*)(Vt + ((size_t)bh * DD + dd) * TT + sb + s0) = w;
    }
}

// ---- flash attention tile body (fully inlined; kc = current K regs, kn = next) ----
static __device__ __forceinline__ void attn_tile(
    const bf16x8 (&kc0)[4], const bf16x8 (&kc1)[4],
    bf16x8 (&kn0)[4], bf16x8 (&kn1)[4],
    const bf16x8 (&qf)[4],
    const short* __restrict__ kbase, const short* __restrict__ vbase, int kb,
    f32x16& o0, f32x16& o1, float& m2, float& ls) {
    const float cc = 0.18033688011112042f;  // 0.125 * log2(e)

    // prefetch NEXT K tile (hidden under this tile's compute)
    int nxt = kb + 64; nxt = (nxt < TT) ? nxt : 0;
    const short* np = kbase + (size_t)nxt * NQKV;
#pragma unroll
    for (int dc = 0; dc < 4; ++dc) kn0[dc] = *(const bf16x8*)(np + dc * 16);
#pragma unroll
    for (int dc = 0; dc < 4; ++dc) kn1[dc] = *(const bf16x8*)(np + (size_t)32 * NQKV + dc * 16);

    // V current tile (consumed at PV, ~500 cyc away)
    const short* vp = vbase + kb;
    bf16x8 vf0[4], vf1[4];
#pragma unroll
    for (int ks = 0; ks < 4; ++ks) vf0[ks] = *(const bf16x8*)(vp + ks * 16);
#pragma unroll
    for (int ks = 0; ks < 4; ++ks) vf1[ks] = *(const bf16x8*)(vp + (size_t)32 * TT + ks * 16);

    // S^T = K * Q^T (col = q, lane-local rows = keys)
    f32x16 s0, s1;
#pragma unroll
    for (int i = 0; i < 16; ++i) { s0[i] = 0.f; s1[i] = 0.f; }
#pragma unroll
    for (int dc = 0; dc < 4; ++dc) s0 = MFMA32(kc0[dc], qf[dc], s0);
#pragma unroll
    for (int dc = 0; dc < 4; ++dc) s1 = MFMA32(kc1[dc], qf[dc], s1);

    // ---- in-register online softmax (lane = one q-row, 32 keys; tree reduce) ----
    float mx = fmaxf(tmax16(s0), tmax16(s1));
    mx = fmaxf(mx, __shfl_xor(mx, 32));   // combine hi/lo half (same q-row)
    float pm2 = mx * cc;
    if (!__all(pm2 - m2 <= 8.0f)) {       // defer-max (T13)
        float nm2 = fmaxf(m2, pm2);
        float alpha = exp2f(m2 - nm2);
        m2 = nm2;
#pragma unroll
        for (int i = 0; i < 16; ++i) { o0[i] *= alpha; o1[i] *= alpha; }
        ls *= alpha;
    }
    float p0[16], p1[16];
#pragma unroll
    for (int i = 0; i < 16; ++i) p0[i] = exp2f(fmaf(s0[i], cc, -m2));
#pragma unroll
    for (int i = 0; i < 16; ++i) p1[i] = exp2f(fmaf(s1[i], cc, -m2));
    float rs = tsum16(p0) + tsum16(p1);
    rs += __shfl_xor(rs, 32);             // combine hi/lo half
    ls += rs;

    // ---- P -> bf16 A-fragments via cvt_pk + permlane32_swap (T12) ----
    uint32_t a0 = cvtpk(p0[0], p0[1]),   a1 = cvtpk(p0[2], p0[3]);
    uint32_t b0 = cvtpk(p0[4], p0[5]),   b1 = cvtpk(p0[6], p0[7]);
    plswap(a0, b0); plswap(a1, b1);
    uint32_t c0 = cvtpk(p0[8], p0[9]),   c1 = cvtpk(p0[10], p0[11]);
    uint32_t d0 = cvtpk(p0[12], p0[13]), d1 = cvtpk(p0[14], p0[15]);
    plswap(c0, d0); plswap(c1, d1);
    uint32_t e0 = cvtpk(p1[0], p1[1]),   e1 = cvtpk(p1[2], p1[3]);
    uint32_t f0 = cvtpk(p1[4], p1[5]),   f1 = cvtpk(p1[6], p1[7]);
    plswap(e0, f0); plswap(e1, f1);
    uint32_t g0 = cvtpk(p1[8], p1[9]),   g1 = cvtpk(p1[10], p1[11]);
    uint32_t h0 = cvtpk(p1[12], p1[13]), h1 = cvtpk(p1[14], p1[15]);
    plswap(g0, h0); plswap(g1, h1);
    u32x4 w0 = {a0, a1, b0, b1};
    u32x4 w1 = {c0, c1, d0, d1};
    u32x4 w2 = {e0, e1, f0, f1};
    u32x4 w3 = {g0, g1, h0, h1};
    bf16x8 pa0 = __builtin_bit_cast(bf16x8, w0);
    bf16x8 pa1 = __builtin_bit_cast(bf16x8, w1);
    bf16x8 pa2 = __builtin_bit_cast(bf16x8, w2);
    bf16x8 pa3 = __builtin_bit_cast(bf16x8, w3);

    // ---- PV: O^T += V^T * P^T ----
    o0 = MFMA32(vf0[0], pa0, o0);
    o0 = MFMA32(vf0[1], pa1, o0);
    o0 = MFMA32(vf0[2], pa2, o0);
    o0 = MFMA32(vf0[3], pa3, o0);
    o1 = MFMA32(vf1[0], pa0, o1);
    o1 = MFMA32(vf1[1], pa1, o1);
    o1 = MFMA32(vf1[2], pa2, o1);
    o1 = MFMA32(vf1[3], pa3, o1);
}

// ---- kernel 5: flash attention, swapped-operand 32x32, reg K-dbuf, no LDS ----
// grid (32 qblocks, 64 bh), 128 thr = 2 waves; each wave 32 q-rows, KVBLK=64.
__global__ __launch_bounds__(128) void attn_fwd(const short* __restrict__ QKV,
                                                const short* __restrict__ Vt,
                                                short* __restrict__ Out) {
    const int qb = blockIdx.x, bh = blockIdx.y;
    const int b = bh >> 4, h = bh & 15;
    const int lane = threadIdx.x & 63, wave = threadIdx.x >> 6;
    const int l31 = lane & 31, hi = lane >> 5;
    const int q0 = qb * 64 + wave * 32;

    // Q fragments (B-operand: col=lane&31=q, k=d=(lane>>5)*8+j), 4 d-chunks of 16
    const short* qptr = QKV + (size_t)(b * TT + q0 + l31) * NQKV + h * 192 + hi * 8;
    bf16x8 qf[4];
#pragma unroll
    for (int dc = 0; dc < 4; ++dc) qf[dc] = *(const bf16x8*)(qptr + dc * 16);

    const short* kbase = QKV + (size_t)(b * TT + l31) * NQKV + h * 192 + 64 + hi * 8;
    const short* vbase = Vt + ((size_t)bh * DD + l31) * TT + hi * 8;

    f32x16 o0, o1;
#pragma unroll
    for (int i = 0; i < 16; ++i) { o0[i] = 0.f; o1[i] = 0.f; }
    float m2 = -1e30f, ls = 0.f;

    // prologue: K tile 0 into A-set
    bf16x8 kA0[4], kA1[4], kB0[4], kB1[4];
#pragma unroll
    for (int dc = 0; dc < 4; ++dc) kA0[dc] = *(const bf16x8*)(kbase + dc * 16);
#pragma unroll
    for (int dc = 0; dc < 4; ++dc) kA1[dc] = *(const bf16x8*)(kbase + (size_t)32 * NQKV + dc * 16);

    for (int kb = 0; kb < TT; kb += 128) {
        attn_tile(kA0, kA1, kB0, kB1, qf, kbase, vbase, kb,      o0, o1, m2, ls);
        attn_tile(kB0, kB1, kA0, kA1, qf, kbase, vbase, kb + 64, o0, o1, m2, ls);
    }

    // epilogue: lane owns q = q0+l31; d = (reg&3) + 8*(reg>>2) + 4*hi (+32 for o1)
    float inv = 1.0f / ls;
    short* orow = Out + (size_t)(b * TT + q0 + l31) * (HH * DD) + h * DD;
#pragma unroll
    for (int g = 0; g < 4; ++g) {
        short4v v0, v1;
#pragma unroll
        for (int r = 0; r < 4; ++r) {
            v0[r] = f2bf(o0[g * 4 + r] * inv);
            v1[r] = f2bf(o1[g * 4 + r] * inv);
        }
        *(short4v*)(orow + g * 8 + hi * 4) = v0;
        *(short4v*)(orow + 32 + g * 8 + hi * 4) = v1;
    }
}

extern "C" void kernel_launch(void* const* d_in, const int* in_sizes, int n_in,
                              void* d_out, int out_size, void* d_ws, size_t ws_size,
                              hipStream_t stream) {
    const float* x      = (const float*)d_in[0];
    const float* w_qkv  = (const float*)d_in[1];
    const float* b_qkv  = (const float*)d_in[2];
    const float* w_proj = (const float*)d_in[3];
    const float* b_proj = (const float*)d_in[4];
    float* out = (float*)d_out;

    char* ws = (char*)d_ws;
    short* xb     = (short*)(ws);                         // 16777216
    short* wqkvt  = (short*)(ws + 16777216);              //  6291456
    short* wprojt = (short*)(ws + 23068672);              //  2097152
    short* qkv    = (short*)(ws + 25165824);              // 50331648
    short* vt     = (short*)(ws + 75497472);              // 16777216
    short* ao     = (short*)(ws + 92274688);              // 16777216

    convert_x<<<8192, 256, 0, stream>>>(x, xb, MM * KK);
    transpose_w<<<dim3(NQKV / 32, KK / 32), 256, 0, stream>>>(w_qkv, wqkvt, KK, NQKV);
    transpose_w<<<dim3(KK / 32, KK / 32), 256, 0, stream>>>(w_proj, wprojt, KK, KK);
    gemm_bt<NQKV, false><<<dim3(NQKV / 128, MM / 128), 256, 0, stream>>>(xb, wqkvt, b_qkv, qkv, KK);
    transpose_v<<<dim3(TT / 64, 64), 256, 0, stream>>>(qkv, vt);
    attn_fwd<<<dim3(TT / 64, 64), 128, 0, stream>>>(qkv, vt, ao);
    gemm_bt<KK, true><<<dim3(KK / 128, MM / 128), 256, 0, stream>>>(ao, wprojt, b_proj, out, KK);
}